// Round 6
// baseline (5595.319 us; speedup 1.0000x reference)
//
#include <hip/hip_runtime.h>

// Problem constants: B=64, S=256, DIM=512, Q=8, K=1024
#define NROWS   16384
#define DIM     512
#define QQ      8
#define KK      1024
#define QOUT_SZ (NROWS * DIM)
#define IDX_SZ  (NROWS * QQ)
#define BK      64

typedef __attribute__((ext_vector_type(8))) short short8x;   // 8 bf16 = 4 VGPR MFMA frag
typedef __attribute__((ext_vector_type(4))) float f32x4;     // MFMA acc

typedef __attribute__((address_space(3))) uint32_t lds_u32;
typedef __attribute__((address_space(1))) const uint32_t ga_u32;
#define GLOBAL_LOAD_LDS16(g, l) \
    __builtin_amdgcn_global_load_lds((ga_u32*)(g), (lds_u32*)(l), 16, 0, 0)

// ---------------- ws layout (~57 MB) ----------------
#define WS_LOSSP_OFF 0                                   // 512 doubles
#define WS_RNORM_OFF (512 * 8)                           // NROWS float
#define WS_ENORM_OFF (WS_RNORM_OFF + NROWS * 4)          // QQ*KK float
#define WS_PD1_OFF   (WS_ENORM_OFF + QQ * KK * 4)        // 4*NROWS float
#define WS_PK1_OFF   (WS_PD1_OFF + 4 * NROWS * 4)        // 4*NROWS int
#define WS_PD2_OFF   (WS_PK1_OFF + 4 * NROWS * 4)        // 4*NROWS float
#define WS_EH_OFF    (WS_PD2_OFF + 4 * NROWS * 4)        // QQ*KK*DIM bf16 (all quantizers)
#define WS_XH_OFF    (WS_EH_OFF + (size_t)QQ * KK * DIM * 2)  // NROWS*DIM bf16
#define WS_RES_OFF   (WS_XH_OFF + (size_t)NROWS * DIM * 2)    // NROWS*DIM fp32 (ground truth)

__device__ inline unsigned short bf16rne(float f) {
    unsigned int u = __float_as_uint(f);
    return (unsigned short)((u + 0x7FFFu + ((u >> 16) & 1u)) >> 16);
}

// enorm over all QQ*KK embed rows (fp32 — same reduction as passing rounds)
__global__ __launch_bounds__(256) void k_enorm(const float4* __restrict__ e4,
                                               float* __restrict__ enorm) {
    int row  = blockIdx.x * 4 + (threadIdx.x >> 6);
    int lane = threadIdx.x & 63;
    float s = 0.f;
#pragma unroll
    for (int i = 0; i < 2; i++) {
        int c = lane + i * 64;
        float4 v = e4[row * (DIM / 4) + c];
        s += v.x * v.x + v.y * v.y + v.z * v.z + v.w * v.w;
    }
#pragma unroll
    for (int off = 32; off; off >>= 1) s += __shfl_down(s, off, 64);
    if (lane == 0) enorm[row] = s;
}

// res = x, rnorm = sum(x^2), Xh = bf16(x). 4 rows/block, wave per row.
__global__ __launch_bounds__(256) void k_prep(const float4* __restrict__ x4,
                                              float4* __restrict__ res4,
                                              float* __restrict__ rnorm,
                                              unsigned short* __restrict__ Xh) {
    int row  = blockIdx.x * 4 + (threadIdx.x >> 6);
    int lane = threadIdx.x & 63;
    float s = 0.f;
#pragma unroll
    for (int i = 0; i < 2; i++) {
        int c = lane + i * 64;
        float4 v = x4[row * (DIM / 4) + c];
        res4[row * (DIM / 4) + c] = v;
        *(ushort4*)&Xh[(size_t)row * DIM + c * 4] =
            make_ushort4(bf16rne(v.x), bf16rne(v.y), bf16rne(v.z), bf16rne(v.w));
        s += v.x * v.x + v.y * v.y + v.z * v.z + v.w * v.w;
    }
#pragma unroll
    for (int off = 32; off; off >>= 1) s += __shfl_down(s, off, 64);
    if (lane == 0) rnorm[row] = s;
}

// cast ALL quantizer codebooks to bf16 once
__global__ __launch_bounds__(256) void k_ecast(const float4* __restrict__ e4,
                                               unsigned short* __restrict__ EhAll) {
    int i = blockIdx.x * 256 + threadIdx.x;
    float4 v = e4[i];
    *(ushort4*)&EhAll[(size_t)i * 4] =
        make_ushort4(bf16rne(v.x), bf16rne(v.y), bf16rne(v.z), bf16rne(v.w));
}

// ---- single-bf16 MFMA distance GEMM + per-row (d1,k1,d2) partials ----
// grid 512 = 128 mt x 4 nt. Block tile: 128 rows x 256 codes, K=512 in 8 chunks of 64.
// LDS k-groups XOR-swizzled by (row&7) — swizzle applied on the global source
// address at staging time (global_load_lds dest is strictly base+lane*16).
__global__ __launch_bounds__(512, 4) void k_gemm(
        const unsigned short* __restrict__ Xh,
        const unsigned short* __restrict__ Eh,    // this quantizer
        const float* __restrict__ enorm_q,
        float* __restrict__ pd1, int* __restrict__ pk1, float* __restrict__ pd2) {
    __shared__ __align__(16) unsigned short sXh[128 * BK];   // 16 KB
    __shared__ __align__(16) unsigned short sEh[256 * BK];   // 32 KB
    __shared__ float sAd1[2][128]; __shared__ int sAk1[2][128]; __shared__ float sAd2[2][128];

    const int tid = threadIdx.x;
    const int l   = tid & 63;
    const int w   = tid >> 6;
    const int wm  = w >> 1;          // row group (0..3): rows wm*32..+31
    const int wn  = w & 1;           // code group (0..1): codes wn*128..+127
    const int mt  = blockIdx.x >> 2;
    const int nt  = blockIdx.x & 3;
    const int l15 = l & 15;
    const int lq4 = l >> 4;          // quad 0..3
    const int srow = l >> 3;         // staging: row within 8-row chunk
    const int sgrp = (l & 7) ^ srow; // staging: swizzled global 8-short group

    f32x4 acc[2][8];
#pragma unroll
    for (int rt = 0; rt < 2; rt++)
#pragma unroll
        for (int ct = 0; ct < 8; ct++) acc[rt][ct] = (f32x4){0.f, 0.f, 0.f, 0.f};

    const unsigned short* gX = Xh + (size_t)(mt * 128) * DIM;
    const unsigned short* gE = Eh + (size_t)(nt * 256) * DIM;
    const int swz = l15 & 7;         // row&7 for all fragment rows this lane touches

    for (int c = 0; c < 8; c++) {
        __syncthreads();
        // stage X: 128 rows x 64 shorts; 2 wave-loads (8 rows each)
#pragma unroll
        for (int i = 0; i < 2; i++) {
            int r = w * 16 + i * 8 + srow;
            GLOBAL_LOAD_LDS16(gX + (size_t)r * DIM + c * BK + sgrp * 8,
                              &sXh[(w * 16 + i * 8) * BK]);
        }
        // stage E: 256 rows x 64 shorts; 4 wave-loads
#pragma unroll
        for (int i = 0; i < 4; i++) {
            int r = w * 32 + i * 8 + srow;
            GLOBAL_LOAD_LDS16(gE + (size_t)r * DIM + c * BK + sgrp * 8,
                              &sEh[(w * 32 + i * 8) * BK]);
        }
        __syncthreads();

#pragma unroll
        for (int ks = 0; ks < 2; ks++) {
            const int g = ((ks * 4 + lq4) ^ swz) * 8;   // swizzled group offset (shorts)
            const int r0 = wm * 32 + l15;
            short8x a0 = *(const short8x*)&sXh[r0 * BK + g];
            short8x a1 = *(const short8x*)&sXh[(r0 + 16) * BK + g];
#pragma unroll
            for (int ct = 0; ct < 8; ct++) {
                const int br = wn * 128 + ct * 16 + l15;
                short8x b = *(const short8x*)&sEh[br * BK + g];
                acc[0][ct] = __builtin_amdgcn_mfma_f32_16x16x32_bf16(a0, b, acc[0][ct], 0, 0, 0);
                acc[1][ct] = __builtin_amdgcn_mfma_f32_16x16x32_bf16(a1, b, acc[1][ct], 0, 0, 0);
            }
        }
    }

    // epilogue: per-lane (d1,k1,d2) over this wave's 128 codes, per row
    float d1[2][4], d2[2][4]; int k1[2][4];
#pragma unroll
    for (int rt = 0; rt < 2; rt++)
#pragma unroll
        for (int r = 0; r < 4; r++) { d1[rt][r] = 3.4e38f; d2[rt][r] = 3.4e38f; k1[rt][r] = 0; }

#pragma unroll
    for (int ct = 0; ct < 8; ct++) {
        int codeg = nt * 256 + wn * 128 + ct * 16 + l15;   // C/D: col = lane&15
        float en = enorm_q[codeg];
#pragma unroll
        for (int rt = 0; rt < 2; rt++)
#pragma unroll
            for (int r = 0; r < 4; r++) {
                float d = en - 2.0f * acc[rt][ct][r];
                if (d < d1[rt][r] || (d == d1[rt][r] && codeg < k1[rt][r])) {
                    d2[rt][r] = d1[rt][r]; d1[rt][r] = d; k1[rt][r] = codeg;
                } else {
                    d2[rt][r] = fminf(d2[rt][r], d);
                }
            }
    }
#pragma unroll
    for (int m = 1; m < 16; m <<= 1) {
#pragma unroll
        for (int rt = 0; rt < 2; rt++)
#pragma unroll
            for (int r = 0; r < 4; r++) {
                float od1 = __shfl_xor(d1[rt][r], m, 64);
                int   ok1 = __shfl_xor(k1[rt][r], m, 64);
                float od2 = __shfl_xor(d2[rt][r], m, 64);
                bool take = (od1 < d1[rt][r]) || (od1 == d1[rt][r] && ok1 < k1[rt][r]);
                float nd2 = take ? fminf(d1[rt][r], od2) : fminf(od1, d2[rt][r]);
                if (take) { d1[rt][r] = od1; k1[rt][r] = ok1; }
                d2[rt][r] = nd2;
            }
    }
    if (l15 == 0) {
#pragma unroll
        for (int rt = 0; rt < 2; rt++)
#pragma unroll
            for (int r = 0; r < 4; r++) {
                int rloc = wm * 32 + rt * 16 + lq4 * 4 + r;   // C/D: row = quad*4 + reg
                sAd1[wn][rloc] = d1[rt][r]; sAk1[wn][rloc] = k1[rt][r]; sAd2[wn][rloc] = d2[rt][r];
            }
    }
    __syncthreads();
    if (tid < 128) {
        float a1 = sAd1[0][tid], a2 = sAd2[0][tid]; int ak = sAk1[0][tid];
        float b1 = sAd1[1][tid], b2 = sAd2[1][tid]; int bk = sAk1[1][tid];
        bool take = (b1 < a1) || (b1 == a1 && bk < ak);
        int grow = mt * 128 + tid;
        pd1[nt * NROWS + grow] = take ? b1 : a1;
        pk1[nt * NROWS + grow] = take ? bk : ak;
        pd2[nt * NROWS + grow] = take ? fminf(a1, b2) : fminf(b1, a2);
    }
}

// fused combine + block-local exact rescan + residual update. 32 rows/block, grid 512.
__global__ __launch_bounds__(512) void k_post(
        const float* __restrict__ pd1, const int* __restrict__ pk1,
        const float* __restrict__ pd2,
        float* __restrict__ res, float* __restrict__ rnorm,
        unsigned short* __restrict__ Xh,
        const float* __restrict__ embed_q, const float* __restrict__ enorm_q,
        double* __restrict__ loss_part, float* __restrict__ out_idx, int q) {
    __shared__ int sIdx[32];
    __shared__ int sList[32];
    __shared__ int sNF;
    __shared__ __align__(16) float sRow[DIM];
    __shared__ float sd[512]; __shared__ int sk[512];
    __shared__ float ls_loss[8];

    const int tid = threadIdx.x;
    const int rbase = blockIdx.x * 32;

    // Phase A: combine 4 nt-partials; flag near-ties (row-scaled margin ~11 sigma)
    if (tid < 64) {
        bool need = false;
        if (tid < 32) {
            int row = rbase + tid;
            float d1 = pd1[row]; int k1 = pk1[row]; float d2 = pd2[row];
#pragma unroll
            for (int nt = 1; nt < 4; nt++) {
                float b1 = pd1[nt * NROWS + row]; int bk = pk1[nt * NROWS + row];
                float b2 = pd2[nt * NROWS + row];
                bool take = (b1 < d1) || (b1 == d1 && bk < k1);
                float nd2 = take ? fminf(d1, b2) : fminf(b1, d2);
                if (take) { d1 = b1; k1 = bk; }
                d2 = nd2;
            }
            sIdx[tid] = k1;
            float thr = 0.05f * sqrtf(rnorm[row]) + 0.02f;
            need = (d2 - d1) < thr;
        }
        unsigned long long m = __ballot(need);
        if (tid == 0) sNF = (int)__popcll(m);
        if (need) {
            int rank = (int)__popcll(m & ((1ull << tid) - 1ull));
            sList[rank] = tid;
        }
    }
    __syncthreads();

    // Phase B: exact fp32 rescan of flagged rows (R1/R2-validated formula & op order)
    const int nf = sNF;
    for (int f = 0; f < nf; f++) {
        int rloc = sList[f];
        int row  = rbase + rloc;
        if (tid < 128)
            *(float4*)&sRow[tid * 4] = *(const float4*)&res[(size_t)row * DIM + tid * 4];
        __syncthreads();
        float rn = rnorm[row];
        float dot0 = 0.f, dot1 = 0.f;
        const float4* e0 = (const float4*)&embed_q[(size_t)tid * DIM];
        const float4* e1 = (const float4*)&embed_q[(size_t)(tid + 512) * DIM];
#pragma unroll 4
        for (int d4 = 0; d4 < 128; d4++) {
            float4 r = *(const float4*)&sRow[d4 * 4];
            float4 a = e0[d4], b = e1[d4];
            dot0 += r.x * a.x; dot0 += r.y * a.y; dot0 += r.z * a.z; dot0 += r.w * a.w;
            dot1 += r.x * b.x; dot1 += r.y * b.y; dot1 += r.z * b.z; dot1 += r.w * b.w;
        }
        float da = (rn + enorm_q[tid])       - 2.0f * dot0;
        float db = (rn + enorm_q[tid + 512]) - 2.0f * dot1;
        float bd; int bk;
        if (da <= db) { bd = da; bk = tid; } else { bd = db; bk = tid + 512; }
        sd[tid] = bd; sk[tid] = bk;
        __syncthreads();
        for (int s = 256; s > 0; s >>= 1) {
            if (tid < s) {
                float o = sd[tid + s]; int ok = sk[tid + s];
                if (o < sd[tid] || (o == sd[tid] && ok < sk[tid])) { sd[tid] = o; sk[tid] = ok; }
            }
            __syncthreads();
        }
        if (tid == 0) sIdx[rloc] = sk[0];
        __syncthreads();
    }

    // Phase C: residual update (exact R2 op order) + Xh regen + loss/rnorm/index
    {
        const int rloc = tid >> 4, seg = tid & 15;
        const int row  = rbase + rloc;
        const int k    = sIdx[rloc];
        const int wave = tid >> 6, lid = tid & 63;
        const size_t base = (size_t)row * DIM + seg * 32;
        const float* erow = embed_q + (size_t)k * DIM + seg * 32;
        float sl = 0.f, sr = 0.f;
#pragma unroll
        for (int u = 0; u < 8; u++) {
            float4 rv = *(const float4*)&res[base + u * 4];
            float4 ev = *(const float4*)(erow + u * 4);
            // t = q - r; q_st = r + t; new_r = r - q_st
            float tx = ev.x - rv.x, ty = ev.y - rv.y, tz = ev.z - rv.z, tw = ev.w - rv.w;
            float qx = rv.x + tx, qy = rv.y + ty, qz = rv.z + tz, qw = rv.w + tw;
            float nx = rv.x - qx, ny = rv.y - qy, nz = rv.z - qz, nw = rv.w - qw;
            *(float4*)&res[base + u * 4] = make_float4(nx, ny, nz, nw);
            *(ushort4*)&Xh[base + u * 4] =
                make_ushort4(bf16rne(nx), bf16rne(ny), bf16rne(nz), bf16rne(nw));
            sl += tx * tx + ty * ty + tz * tz + tw * tw;
            sr += nx * nx + ny * ny + nz * nz + nw * nw;
        }
        if (seg == 0) out_idx[(size_t)row * QQ + q] = (float)k;
        float srr = sr;
#pragma unroll
        for (int m = 1; m < 16; m <<= 1) srr += __shfl_xor(srr, m, 64);
        if (seg == 0) rnorm[row] = srr;
#pragma unroll
        for (int m = 1; m < 64; m <<= 1) sl += __shfl_xor(sl, m, 64);
        if (lid == 0) ls_loss[wave] = sl;
        __syncthreads();
        if (tid == 0) {
            float s = 0.f;
#pragma unroll
            for (int w = 0; w < 8; w++) s += ls_loss[w];
            double cur = (q == 0) ? 0.0 : loss_part[blockIdx.x];
            loss_part[blockIdx.x] = cur + (double)s;
        }
    }
}

// qout = x - res_final ; block 0 reduces loss partials
__global__ __launch_bounds__(256) void k_final(const float4* __restrict__ x4,
                                               const float4* __restrict__ res4,
                                               float4* __restrict__ out4,
                                               const double* __restrict__ loss_part,
                                               float* __restrict__ out_scalar) {
    int i = blockIdx.x * 256 + threadIdx.x;
    float4 a = x4[i], b = res4[i];
    out4[i] = make_float4(a.x - b.x, a.y - b.y, a.z - b.z, a.w - b.w);
    if (blockIdx.x == 0 && threadIdx.x < 64) {
        double s = 0.0;
#pragma unroll
        for (int j = 0; j < 8; j++) s += loss_part[threadIdx.x + 64 * j];
#pragma unroll
        for (int m = 1; m < 64; m <<= 1) s += __shfl_xor(s, m, 64);
        if (threadIdx.x == 0) out_scalar[0] = (float)(s * 2.0 / (double)QOUT_SZ);
    }
}

extern "C" void kernel_launch(void* const* d_in, const int* in_sizes, int n_in,
                              void* d_out, int out_size, void* d_ws, size_t ws_size,
                              hipStream_t stream) {
    const float* x      = (const float*)d_in[0];   // [NROWS][DIM]
    const float* embeds = (const float*)d_in[1];   // [QQ][KK][DIM]

    char*   ws        = (char*)d_ws;
    double* loss_part = (double*)(ws + WS_LOSSP_OFF);
    float*  rnorm     = (float*) (ws + WS_RNORM_OFF);
    float*  enorm     = (float*) (ws + WS_ENORM_OFF);
    float*  pd1       = (float*) (ws + WS_PD1_OFF);
    int*    pk1       = (int*)   (ws + WS_PK1_OFF);
    float*  pd2       = (float*) (ws + WS_PD2_OFF);
    unsigned short* EhAll = (unsigned short*)(ws + WS_EH_OFF);
    unsigned short* Xh    = (unsigned short*)(ws + WS_XH_OFF);
    float*  res       = (float*) (ws + WS_RES_OFF);

    float* out_q      = (float*)d_out;
    float* out_idx    = out_q + QOUT_SZ;
    float* out_scalar = out_q + QOUT_SZ + IDX_SZ;

    k_enorm<<<(QQ * KK) / 4, 256, 0, stream>>>((const float4*)embeds, enorm);
    k_prep <<<NROWS / 4, 256, 0, stream>>>((const float4*)x, (float4*)res, rnorm, Xh);
    k_ecast<<<(QQ * KK * DIM) / 4 / 256, 256, 0, stream>>>((const float4*)embeds, EhAll);

    for (int q = 0; q < QQ; q++) {
        const float* embed_q = embeds + (size_t)q * KK * DIM;
        const float* enorm_q = enorm + q * KK;
        const unsigned short* Eh_q = EhAll + (size_t)q * KK * DIM;
        k_gemm<<<512, 512, 0, stream>>>(Xh, Eh_q, enorm_q, pd1, pk1, pd2);
        k_post<<<512, 512, 0, stream>>>(pd1, pk1, pd2, res, rnorm, Xh,
                                        embed_q, enorm_q, loss_part, out_idx, q);
    }

    k_final<<<QOUT_SZ / 4 / 256, 256, 0, stream>>>((const float4*)x, (const float4*)res,
                                                   (float4*)d_out, loss_part, out_scalar);
}

// Round 7
// 1281.135 us; speedup vs baseline: 4.3675x; 4.3675x over previous
//
#include <hip/hip_runtime.h>

// Problem constants: B=64, S=256, DIM=512, Q=8, K=1024
#define NROWS   16384
#define DIM     512
#define QQ      8
#define KK      1024
#define QOUT_SZ (NROWS * DIM)
#define IDX_SZ  (NROWS * QQ)
#define BK      64

// flag threshold: thr = FLAG_REL*||r|| + FLAG_ABS  (pairwise bf16-hh dist error
// sigma ~ 0.0045*||r||; 1024-trial worst ~0.015*||r||; 2.6x headroom)
#define FLAG_REL 0.04f
#define FLAG_ABS 0.02f

typedef __attribute__((ext_vector_type(8))) short short8x;   // 8 bf16 = 4 VGPR MFMA frag
typedef __attribute__((ext_vector_type(4))) float f32x4;     // MFMA acc

typedef __attribute__((address_space(3))) uint32_t lds_u32;
typedef __attribute__((address_space(1))) const uint32_t ga_u32;
#define GLOBAL_LOAD_LDS16(g, l) \
    __builtin_amdgcn_global_load_lds((ga_u32*)(g), (lds_u32*)(l), 16, 0, 0)

// ---------------- ws layout (~58 MB) ----------------
#define WS_LOSSP_OFF 0                                   // 512 doubles
#define WS_LOSSR_OFF (512 * 8)                           // 1 double (rare-path loss)
#define WS_NFLAG_OFF (WS_LOSSR_OFF + 16)                 // 1 int (+pad)
#define WS_FLAG_OFF  (WS_NFLAG_OFF + 16)                 // NROWS int
#define WS_RNORM_OFF (WS_FLAG_OFF + NROWS * 4)           // NROWS float
#define WS_ENORM_OFF (WS_RNORM_OFF + NROWS * 4)          // QQ*KK float
#define WS_PD1_OFF   (WS_ENORM_OFF + QQ * KK * 4)        // 4*NROWS float
#define WS_PK1_OFF   (WS_PD1_OFF + 4 * NROWS * 4)        // 4*NROWS int
#define WS_PD2_OFF   (WS_PK1_OFF + 4 * NROWS * 4)        // 4*NROWS float
#define WS_PK2_OFF   (WS_PD2_OFF + 4 * NROWS * 4)        // 4*NROWS int
#define WS_PD3_OFF   (WS_PK2_OFF + 4 * NROWS * 4)        // 4*NROWS float
#define WS_EH_OFF    (WS_PD3_OFF + 4 * NROWS * 4)        // QQ*KK*DIM bf16
#define WS_XH_OFF    (WS_EH_OFF + (size_t)QQ * KK * DIM * 2)  // NROWS*DIM bf16
#define WS_RES_OFF   (WS_XH_OFF + (size_t)NROWS * DIM * 2)    // NROWS*DIM fp32

__device__ inline unsigned short bf16rne(float f) {
    unsigned int u = __float_as_uint(f);
    return (unsigned short)((u + 0x7FFFu + ((u >> 16) & 1u)) >> 16);
}

// merge two sorted (d1,k1,d2,k2,d3) triples -> mine
__device__ inline void merge3(float& d1, int& k1, float& d2, int& k2, float& d3,
                              float o1, int q1, float o2, int q2, float o3) {
    bool bf = (o1 < d1) || (o1 == d1 && q1 < k1);
    float n1d, n2d, n3d; int n1k, n2k;
    if (bf) {
        n1d = o1; n1k = q1;
        bool b2 = (o2 < d1) || (o2 == d1 && q2 < k1);
        if (b2) { n2d = o2; n2k = q2; n3d = fminf(o3, d1); }
        else    { n2d = d1; n2k = k1; n3d = fminf(o2, d2); }
    } else {
        n1d = d1; n1k = k1;
        bool a2 = (d2 < o1) || (d2 == o1 && k2 < q1);
        if (a2) { n2d = d2; n2k = k2; n3d = fminf(d3, o1); }
        else    { n2d = o1; n2k = q1; n3d = fminf(d2, o2); }
    }
    d1 = n1d; k1 = n1k; d2 = n2d; k2 = n2k; d3 = n3d;
}

// enorm over all QQ*KK embed rows (fp32 — same reduction as passing rounds)
__global__ __launch_bounds__(256) void k_enorm(const float4* __restrict__ e4,
                                               float* __restrict__ enorm) {
    int row  = blockIdx.x * 4 + (threadIdx.x >> 6);
    int lane = threadIdx.x & 63;
    float s = 0.f;
#pragma unroll
    for (int i = 0; i < 2; i++) {
        int c = lane + i * 64;
        float4 v = e4[row * (DIM / 4) + c];
        s += v.x * v.x + v.y * v.y + v.z * v.z + v.w * v.w;
    }
#pragma unroll
    for (int off = 32; off; off >>= 1) s += __shfl_down(s, off, 64);
    if (lane == 0) enorm[row] = s;
}

// res = x, rnorm = sum(x^2), Xh = bf16(x); block 0 zeroes loss_rare
__global__ __launch_bounds__(256) void k_prep(const float4* __restrict__ x4,
                                              float4* __restrict__ res4,
                                              float* __restrict__ rnorm,
                                              unsigned short* __restrict__ Xh,
                                              double* __restrict__ loss_rare) {
    if (blockIdx.x == 0 && threadIdx.x == 0) *loss_rare = 0.0;
    int row  = blockIdx.x * 4 + (threadIdx.x >> 6);
    int lane = threadIdx.x & 63;
    float s = 0.f;
#pragma unroll
    for (int i = 0; i < 2; i++) {
        int c = lane + i * 64;
        float4 v = x4[row * (DIM / 4) + c];
        res4[row * (DIM / 4) + c] = v;
        *(ushort4*)&Xh[(size_t)row * DIM + c * 4] =
            make_ushort4(bf16rne(v.x), bf16rne(v.y), bf16rne(v.z), bf16rne(v.w));
        s += v.x * v.x + v.y * v.y + v.z * v.z + v.w * v.w;
    }
#pragma unroll
    for (int off = 32; off; off >>= 1) s += __shfl_down(s, off, 64);
    if (lane == 0) rnorm[row] = s;
}

// cast ALL quantizer codebooks to bf16 once
__global__ __launch_bounds__(256) void k_ecast(const float4* __restrict__ e4,
                                               unsigned short* __restrict__ EhAll) {
    int i = blockIdx.x * 256 + threadIdx.x;
    float4 v = e4[i];
    *(ushort4*)&EhAll[(size_t)i * 4] =
        make_ushort4(bf16rne(v.x), bf16rne(v.y), bf16rne(v.z), bf16rne(v.w));
}

// ---- single-bf16 MFMA distance GEMM + per-row top-3 partials ----
// grid 512 = 128 mt x 4 nt. Block tile: 128 rows x 256 codes, K=512 in 8 chunks of 64.
__global__ __launch_bounds__(512, 4) void k_gemm(
        const unsigned short* __restrict__ Xh,
        const unsigned short* __restrict__ Eh,    // this quantizer
        const float* __restrict__ enorm_q,
        float* __restrict__ pd1, int* __restrict__ pk1,
        float* __restrict__ pd2, int* __restrict__ pk2,
        float* __restrict__ pd3, int* __restrict__ nflag) {
    __shared__ __align__(16) unsigned short sXh[128 * BK];   // 16 KB
    __shared__ __align__(16) unsigned short sEh[256 * BK];   // 32 KB
    __shared__ float sD1[2][128]; __shared__ int sK1[2][128];
    __shared__ float sD2[2][128]; __shared__ int sK2[2][128];
    __shared__ float sD3[2][128];

    const int tid = threadIdx.x;
    if (blockIdx.x == 0 && tid == 0) *nflag = 0;   // reset flag list for this step
    const int l   = tid & 63;
    const int w   = tid >> 6;
    const int wm  = w >> 1;
    const int wn  = w & 1;
    const int mt  = blockIdx.x >> 2;
    const int nt  = blockIdx.x & 3;
    const int l15 = l & 15;
    const int lq4 = l >> 4;
    const int srow = l >> 3;
    const int sgrp = (l & 7) ^ srow;

    f32x4 acc[2][8];
#pragma unroll
    for (int rt = 0; rt < 2; rt++)
#pragma unroll
        for (int ct = 0; ct < 8; ct++) acc[rt][ct] = (f32x4){0.f, 0.f, 0.f, 0.f};

    const unsigned short* gX = Xh + (size_t)(mt * 128) * DIM;
    const unsigned short* gE = Eh + (size_t)(nt * 256) * DIM;
    const int swz = l15 & 7;

    for (int c = 0; c < 8; c++) {
        __syncthreads();
#pragma unroll
        for (int i = 0; i < 2; i++) {
            int r = w * 16 + i * 8 + srow;
            GLOBAL_LOAD_LDS16(gX + (size_t)r * DIM + c * BK + sgrp * 8,
                              &sXh[(w * 16 + i * 8) * BK]);
        }
#pragma unroll
        for (int i = 0; i < 4; i++) {
            int r = w * 32 + i * 8 + srow;
            GLOBAL_LOAD_LDS16(gE + (size_t)r * DIM + c * BK + sgrp * 8,
                              &sEh[(w * 32 + i * 8) * BK]);
        }
        __syncthreads();

#pragma unroll
        for (int ks = 0; ks < 2; ks++) {
            const int g = ((ks * 4 + lq4) ^ swz) * 8;
            const int r0 = wm * 32 + l15;
            short8x a0 = *(const short8x*)&sXh[r0 * BK + g];
            short8x a1 = *(const short8x*)&sXh[(r0 + 16) * BK + g];
#pragma unroll
            for (int ct = 0; ct < 8; ct++) {
                const int br = wn * 128 + ct * 16 + l15;
                short8x b = *(const short8x*)&sEh[br * BK + g];
                acc[0][ct] = __builtin_amdgcn_mfma_f32_16x16x32_bf16(a0, b, acc[0][ct], 0, 0, 0);
                acc[1][ct] = __builtin_amdgcn_mfma_f32_16x16x32_bf16(a1, b, acc[1][ct], 0, 0, 0);
            }
        }
    }

    // epilogue: per-lane top-3 over this wave's 128 codes, per row slot
    float d1[2][4], d2[2][4], d3[2][4]; int k1[2][4], k2[2][4];
#pragma unroll
    for (int rt = 0; rt < 2; rt++)
#pragma unroll
        for (int r = 0; r < 4; r++) {
            d1[rt][r] = 3.4e38f; d2[rt][r] = 3.4e38f; d3[rt][r] = 3.4e38f;
            k1[rt][r] = 0; k2[rt][r] = 0;
        }

#pragma unroll
    for (int ct = 0; ct < 8; ct++) {
        int codeg = nt * 256 + wn * 128 + ct * 16 + l15;   // C/D: col = lane&15
        float en = enorm_q[codeg];
#pragma unroll
        for (int rt = 0; rt < 2; rt++)
#pragma unroll
            for (int r = 0; r < 4; r++) {
                float d = en - 2.0f * acc[rt][ct][r];
                if (d < d1[rt][r] || (d == d1[rt][r] && codeg < k1[rt][r])) {
                    d3[rt][r] = d2[rt][r];
                    d2[rt][r] = d1[rt][r]; k2[rt][r] = k1[rt][r];
                    d1[rt][r] = d; k1[rt][r] = codeg;
                } else if (d < d2[rt][r] || (d == d2[rt][r] && codeg < k2[rt][r])) {
                    d3[rt][r] = d2[rt][r];
                    d2[rt][r] = d; k2[rt][r] = codeg;
                } else {
                    d3[rt][r] = fminf(d3[rt][r], d);
                }
            }
    }
#pragma unroll
    for (int m = 1; m < 16; m <<= 1) {
#pragma unroll
        for (int rt = 0; rt < 2; rt++)
#pragma unroll
            for (int r = 0; r < 4; r++) {
                float o1 = __shfl_xor(d1[rt][r], m, 64);
                int   q1 = __shfl_xor(k1[rt][r], m, 64);
                float o2 = __shfl_xor(d2[rt][r], m, 64);
                int   q2 = __shfl_xor(k2[rt][r], m, 64);
                float o3 = __shfl_xor(d3[rt][r], m, 64);
                merge3(d1[rt][r], k1[rt][r], d2[rt][r], k2[rt][r], d3[rt][r],
                       o1, q1, o2, q2, o3);
            }
    }
    if (l15 == 0) {
#pragma unroll
        for (int rt = 0; rt < 2; rt++)
#pragma unroll
            for (int r = 0; r < 4; r++) {
                int rloc = wm * 32 + rt * 16 + lq4 * 4 + r;   // C/D: row = quad*4 + reg
                sD1[wn][rloc] = d1[rt][r]; sK1[wn][rloc] = k1[rt][r];
                sD2[wn][rloc] = d2[rt][r]; sK2[wn][rloc] = k2[rt][r];
                sD3[wn][rloc] = d3[rt][r];
            }
    }
    __syncthreads();
    if (tid < 128) {
        float a1 = sD1[0][tid], a2 = sD2[0][tid], a3 = sD3[0][tid];
        int   ak1 = sK1[0][tid], ak2 = sK2[0][tid];
        merge3(a1, ak1, a2, ak2, a3,
               sD1[1][tid], sK1[1][tid], sD2[1][tid], sK2[1][tid], sD3[1][tid]);
        int grow = mt * 128 + tid;
        pd1[nt * NROWS + grow] = a1; pk1[nt * NROWS + grow] = ak1;
        pd2[nt * NROWS + grow] = a2; pk2[nt * NROWS + grow] = ak2;
        pd3[nt * NROWS + grow] = a3;
    }
}

// fused combine + exact top-2 decision + residual update. 32 rows/block, grid 512.
// Rows whose 3rd-best is within thr of best go to the global flag list (k_rare).
__global__ __launch_bounds__(512) void k_post(
        const float* __restrict__ pd1, const int* __restrict__ pk1,
        const float* __restrict__ pd2, const int* __restrict__ pk2,
        const float* __restrict__ pd3,
        float* __restrict__ res, float* __restrict__ rnorm,
        unsigned short* __restrict__ Xh,
        const float* __restrict__ embed_q, const float* __restrict__ enorm_q,
        double* __restrict__ loss_part, float* __restrict__ out_idx,
        int* __restrict__ nflag, int* __restrict__ flag_list, int q) {
    __shared__ int sIdx1[32], sIdx2[32], sFlag[32];
    __shared__ float ls_loss[8];

    const int tid = threadIdx.x;
    const int rbase = blockIdx.x * 32;

    // Phase A: combine 4 nt top-3 partials; flag rows with d3-d1 < thr
    if (tid < 32) {
        int row = rbase + tid;
        float d1 = pd1[row], d2 = pd2[row], d3 = pd3[row];
        int   k1 = pk1[row], k2 = pk2[row];
#pragma unroll
        for (int nt = 1; nt < 4; nt++) {
            merge3(d1, k1, d2, k2, d3,
                   pd1[nt * NROWS + row], pk1[nt * NROWS + row],
                   pd2[nt * NROWS + row], pk2[nt * NROWS + row],
                   pd3[nt * NROWS + row]);
        }
        sIdx1[tid] = k1; sIdx2[tid] = k2;
        float thr = FLAG_REL * sqrtf(rnorm[row]) + FLAG_ABS;
        int fl = (d3 - d1) < thr;
        sFlag[tid] = fl;
        if (fl) { int p = atomicAdd(nflag, 1); flag_list[p] = row; }
    }
    __syncthreads();

    // Phase B+C: exact fp32 dists of k1,k2 (16 thr/row), pick winner, update
    {
        const int rloc = tid >> 4, seg = tid & 15;
        const int row  = rbase + rloc;
        const int k1   = sIdx1[rloc], k2 = sIdx2[rloc];
        const int fl   = sFlag[rloc];
        const int wave = tid >> 6, lid = tid & 63;
        const size_t base = (size_t)row * DIM + seg * 32;
        const float* e1p = embed_q + (size_t)k1 * DIM + seg * 32;
        const float* e2p = embed_q + (size_t)k2 * DIM + seg * 32;
        float rn = rnorm[row];
        float4 rv[8];
        float dot1 = 0.f, dot2 = 0.f;
#pragma unroll
        for (int u = 0; u < 8; u++) {
            rv[u] = *(const float4*)&res[base + u * 4];
            float4 a = *(const float4*)(e1p + u * 4);
            float4 b = *(const float4*)(e2p + u * 4);
            dot1 += rv[u].x * a.x; dot1 += rv[u].y * a.y;
            dot1 += rv[u].z * a.z; dot1 += rv[u].w * a.w;
            dot2 += rv[u].x * b.x; dot2 += rv[u].y * b.y;
            dot2 += rv[u].z * b.z; dot2 += rv[u].w * b.w;
        }
#pragma unroll
        for (int m = 1; m < 16; m <<= 1) {
            dot1 += __shfl_xor(dot1, m, 64);
            dot2 += __shfl_xor(dot2, m, 64);
        }
        float da = (rn + enorm_q[k1]) - 2.0f * dot1;
        float db = (rn + enorm_q[k2]) - 2.0f * dot2;
        int kw = (db < da || (db == da && k2 < k1)) ? k2 : k1;

        float sl = 0.f;
        if (!fl) {
            const float* ep = embed_q + (size_t)kw * DIM + seg * 32;
            float sr = 0.f;
#pragma unroll
            for (int u = 0; u < 8; u++) {
                float4 ev = *(const float4*)(ep + u * 4);
                // t = q - r; q_st = r + t; new_r = r - q_st  (exact R2 op order)
                float tx = ev.x - rv[u].x, ty = ev.y - rv[u].y;
                float tz = ev.z - rv[u].z, tw = ev.w - rv[u].w;
                float qx = rv[u].x + tx, qy = rv[u].y + ty;
                float qz = rv[u].z + tz, qw = rv[u].w + tw;
                float nx = rv[u].x - qx, ny = rv[u].y - qy;
                float nz = rv[u].z - qz, nw = rv[u].w - qw;
                *(float4*)&res[base + u * 4] = make_float4(nx, ny, nz, nw);
                *(ushort4*)&Xh[base + u * 4] =
                    make_ushort4(bf16rne(nx), bf16rne(ny), bf16rne(nz), bf16rne(nw));
                sl += tx * tx + ty * ty + tz * tz + tw * tw;
                sr += nx * nx + ny * ny + nz * nz + nw * nw;
            }
            if (seg == 0) out_idx[(size_t)row * QQ + q] = (float)kw;
            float srr = sr;
#pragma unroll
            for (int m = 1; m < 16; m <<= 1) srr += __shfl_xor(srr, m, 64);
            if (seg == 0) rnorm[row] = srr;
        }
#pragma unroll
        for (int m = 1; m < 64; m <<= 1) sl += __shfl_xor(sl, m, 64);
        if (lid == 0) ls_loss[wave] = sl;
    }
    __syncthreads();
    if (tid == 0) {
        float s = 0.f;
#pragma unroll
        for (int w = 0; w < 8; w++) s += ls_loss[w];
        double cur = (q == 0) ? 0.0 : loss_part[blockIdx.x];
        loss_part[blockIdx.x] = cur + (double)s;
    }
}

// rare full fp32 rescan + update: one block per flagged row, grid-stride.
__global__ __launch_bounds__(256) void k_rare(
        const int* __restrict__ nflag, const int* __restrict__ flag_list,
        float* __restrict__ res, float* __restrict__ rnorm,
        unsigned short* __restrict__ Xh,
        const float* __restrict__ embed_q, const float* __restrict__ enorm_q,
        double* __restrict__ loss_rare, float* __restrict__ out_idx, int q) {
    __shared__ __align__(16) float rrow[DIM];
    __shared__ float sd[256]; __shared__ int sk[256];
    __shared__ float ls[4], rs[4];
    const int tid = threadIdx.x;
    const int nf = *nflag;
    for (int f = blockIdx.x; f < nf; f += gridDim.x) {
        int row = flag_list[f];
        __syncthreads();
        if (tid < 128)
            *(float4*)&rrow[tid * 4] = *(const float4*)&res[(size_t)row * DIM + tid * 4];
        __syncthreads();
        float rn = rnorm[row];
        float dot[4] = {0.f, 0.f, 0.f, 0.f};
        const float4* e0 = (const float4*)&embed_q[(size_t)(tid + 0)   * DIM];
        const float4* e1 = (const float4*)&embed_q[(size_t)(tid + 256) * DIM];
        const float4* e2 = (const float4*)&embed_q[(size_t)(tid + 512) * DIM];
        const float4* e3 = (const float4*)&embed_q[(size_t)(tid + 768) * DIM];
#pragma unroll 4
        for (int d4 = 0; d4 < 128; d4++) {
            float4 r = *(const float4*)&rrow[d4 * 4];
            float4 a = e0[d4], b = e1[d4], c = e2[d4], e = e3[d4];
            dot[0] += r.x * a.x; dot[0] += r.y * a.y; dot[0] += r.z * a.z; dot[0] += r.w * a.w;
            dot[1] += r.x * b.x; dot[1] += r.y * b.y; dot[1] += r.z * b.z; dot[1] += r.w * b.w;
            dot[2] += r.x * c.x; dot[2] += r.y * c.y; dot[2] += r.z * c.z; dot[2] += r.w * c.w;
            dot[3] += r.x * e.x; dot[3] += r.y * e.y; dot[3] += r.z * e.z; dot[3] += r.w * e.w;
        }
        float bd = 3.4e38f; int bk = 0;
#pragma unroll
        for (int cc = 0; cc < 4; cc++) {
            int k = tid + cc * 256;
            float dist = (rn + enorm_q[k]) - 2.0f * dot[cc];
            if (dist < bd || (dist == bd && k < bk)) { bd = dist; bk = k; }
        }
        sd[tid] = bd; sk[tid] = bk;
        __syncthreads();
        for (int s = 128; s > 0; s >>= 1) {
            if (tid < s) {
                float o = sd[tid + s]; int ok = sk[tid + s];
                if (o < sd[tid] || (o == sd[tid] && ok < sk[tid])) { sd[tid] = o; sk[tid] = ok; }
            }
            __syncthreads();
        }
        const int kbest = sk[0];
        // update this row
        float sl = 0.f, sr = 0.f;
        if (tid < 128) {
            float4 rv = *(const float4*)&rrow[tid * 4];
            float4 ev = *(const float4*)&embed_q[(size_t)kbest * DIM + tid * 4];
            float tx = ev.x - rv.x, ty = ev.y - rv.y, tz = ev.z - rv.z, tw = ev.w - rv.w;
            float qx = rv.x + tx, qy = rv.y + ty, qz = rv.z + tz, qw = rv.w + tw;
            float nx = rv.x - qx, ny = rv.y - qy, nz = rv.z - qz, nw = rv.w - qw;
            *(float4*)&res[(size_t)row * DIM + tid * 4] = make_float4(nx, ny, nz, nw);
            *(ushort4*)&Xh[(size_t)row * DIM + tid * 4] =
                make_ushort4(bf16rne(nx), bf16rne(ny), bf16rne(nz), bf16rne(nw));
            sl = tx * tx + ty * ty + tz * tz + tw * tw;
            sr = nx * nx + ny * ny + nz * nz + nw * nw;
        }
        int lid = tid & 63, wv = tid >> 6;
#pragma unroll
        for (int m = 1; m < 64; m <<= 1) {
            sl += __shfl_xor(sl, m, 64);
            sr += __shfl_xor(sr, m, 64);
        }
        if (lid == 0) { ls[wv] = sl; rs[wv] = sr; }
        __syncthreads();
        if (tid == 0) {
            float tl = ls[0] + ls[1] + ls[2] + ls[3];
            float tr = rs[0] + rs[1] + rs[2] + rs[3];
            rnorm[row] = tr;
            atomicAdd(loss_rare, (double)tl);
            out_idx[(size_t)row * QQ + q] = (float)kbest;
        }
        __syncthreads();
    }
}

// qout = x - res_final ; block 0 reduces loss partials + rare loss
__global__ __launch_bounds__(256) void k_final(const float4* __restrict__ x4,
                                               const float4* __restrict__ res4,
                                               float4* __restrict__ out4,
                                               const double* __restrict__ loss_part,
                                               const double* __restrict__ loss_rare,
                                               float* __restrict__ out_scalar) {
    int i = blockIdx.x * 256 + threadIdx.x;
    float4 a = x4[i], b = res4[i];
    out4[i] = make_float4(a.x - b.x, a.y - b.y, a.z - b.z, a.w - b.w);
    if (blockIdx.x == 0 && threadIdx.x < 64) {
        double s = 0.0;
#pragma unroll
        for (int j = 0; j < 8; j++) s += loss_part[threadIdx.x + 64 * j];
#pragma unroll
        for (int m = 1; m < 64; m <<= 1) s += __shfl_xor(s, m, 64);
        if (threadIdx.x == 0)
            out_scalar[0] = (float)((s + *loss_rare) * 2.0 / (double)QOUT_SZ);
    }
}

extern "C" void kernel_launch(void* const* d_in, const int* in_sizes, int n_in,
                              void* d_out, int out_size, void* d_ws, size_t ws_size,
                              hipStream_t stream) {
    const float* x      = (const float*)d_in[0];   // [NROWS][DIM]
    const float* embeds = (const float*)d_in[1];   // [QQ][KK][DIM]

    char*   ws        = (char*)d_ws;
    double* loss_part = (double*)(ws + WS_LOSSP_OFF);
    double* loss_rare = (double*)(ws + WS_LOSSR_OFF);
    int*    nflag     = (int*)   (ws + WS_NFLAG_OFF);
    int*    flag_list = (int*)   (ws + WS_FLAG_OFF);
    float*  rnorm     = (float*) (ws + WS_RNORM_OFF);
    float*  enorm     = (float*) (ws + WS_ENORM_OFF);
    float*  pd1       = (float*) (ws + WS_PD1_OFF);
    int*    pk1       = (int*)   (ws + WS_PK1_OFF);
    float*  pd2       = (float*) (ws + WS_PD2_OFF);
    int*    pk2       = (int*)   (ws + WS_PK2_OFF);
    float*  pd3       = (float*) (ws + WS_PD3_OFF);
    unsigned short* EhAll = (unsigned short*)(ws + WS_EH_OFF);
    unsigned short* Xh    = (unsigned short*)(ws + WS_XH_OFF);
    float*  res       = (float*) (ws + WS_RES_OFF);

    float* out_q      = (float*)d_out;
    float* out_idx    = out_q + QOUT_SZ;
    float* out_scalar = out_q + QOUT_SZ + IDX_SZ;

    k_enorm<<<(QQ * KK) / 4, 256, 0, stream>>>((const float4*)embeds, enorm);
    k_prep <<<NROWS / 4, 256, 0, stream>>>((const float4*)x, (float4*)res, rnorm, Xh, loss_rare);
    k_ecast<<<(QQ * KK * DIM) / 4 / 256, 256, 0, stream>>>((const float4*)embeds, EhAll);

    for (int q = 0; q < QQ; q++) {
        const float* embed_q = embeds + (size_t)q * KK * DIM;
        const float* enorm_q = enorm + q * KK;
        const unsigned short* Eh_q = EhAll + (size_t)q * KK * DIM;
        k_gemm<<<512, 512, 0, stream>>>(Xh, Eh_q, enorm_q, pd1, pk1, pd2, pk2, pd3, nflag);
        k_post<<<512, 512, 0, stream>>>(pd1, pk1, pd2, pk2, pd3, res, rnorm, Xh,
                                        embed_q, enorm_q, loss_part, out_idx,
                                        nflag, flag_list, q);
        k_rare<<<128, 256, 0, stream>>>(nflag, flag_list, res, rnorm, Xh,
                                        embed_q, enorm_q, loss_rare, out_idx, q);
    }

    k_final<<<QOUT_SZ / 4 / 256, 256, 0, stream>>>((const float4*)x, (const float4*)res,
                                                   (float4*)d_out, loss_part, loss_rare,
                                                   out_scalar);
}